// Round 19
// baseline (406.598 us; speedup 1.0000x reference)
//
#include <hip/hip_runtime.h>

#define LROW    2904
#define PERIOD  24
#define CYC     121          // cycles; odd -> median = 0-indexed rank 60
#define NF      207
#define NB      64
#define NROWS   13248
#define FCH     8            // features per k_median block
#define NCH     26           // ceil(207/8)
#define KPADW   9            // padded f-stride (u32) in LDS keys
#define KLDS    (PERIOD * 61 * KPADW)   // 13176 u32 = 52.7 KB
#define NT      256
#define LTILE   24
#define NLT     121
#define K2GRID  (NB * NLT)   // 7744
#define K2CHUNK (K2GRID / 8)
#define R13     (1.f / 13.f)

typedef unsigned short us2 __attribute__((ext_vector_type(2)));

__device__ __forceinline__ int clampi(int i) {
    return i < 0 ? 0 : (i >= LROW ? LROW - 1 : i);
}
// 16-bit fixed-point key: grid 2^-12, range [-8,8). Monotone (trunc+clamp).
__device__ __forceinline__ unsigned quantk(float d) {
    int ki = (int)fmaf(d, 4096.f, 32768.f);
    ki = ki < 0 ? 0 : (ki > 65535 ? 65535 : ki);
    return (unsigned)ki;
}
__device__ __forceinline__ float dqmid(unsigned k) {
    return ((float)(int)k - 32767.5f) * (1.f / 4096.f);
}

// Split-K rank select (R18): lane pair (t, t^1) shares one select; half0 owns
// slots 0..30 (62 halfwords), half1 slots 31..60 (60 halfwords incl sentinel)
// + zero pad. Keys in REGISTERS (loaded once from LDS). Largest T with
// cnt_ge(T) >= thr over 122 halfwords; thr=62 -> v[60], 61 -> v[61], 63 -> v[59].
__device__ __forceinline__ unsigned selN_split(const unsigned (&K)[31], int thr) {
    unsigned T = 0;
    const us2 one2 = __builtin_bit_cast(us2, 0x00010001u);
    for (int bit = 15; bit >= 0; --bit) {
        unsigned Tp = T | (1u << bit);
        unsigned tm32 = (Tp - 1u) | ((Tp - 1u) << 16);
        us2 tm2 = __builtin_bit_cast(us2, tm32);
        us2 acc = __builtin_bit_cast(us2, 0u);
        #pragma unroll
        for (int s = 0; s < 31; ++s) {
            us2 kv = __builtin_bit_cast(us2, K[s]);
            us2 dd = __builtin_elementwise_sub_sat(kv, tm2);  // max(0,k-(Tp-1))
            us2 mm = __builtin_elementwise_min(dd, one2);     // 1 iff k >= Tp
            acc = acc + mm;
        }
        unsigned a = __builtin_bit_cast(unsigned, acc);
        int cnt = (int)(a & 0xFFFFu) + (int)(a >> 16);
        cnt += __shfl_xor(cnt, 1);                            // pair total
        if (cnt >= thr) T = Tp;
    }
    return T;
}

__device__ __forceinline__ void loadK31(const unsigned* keyl, int p, int f,
                                        int half, unsigned (&K)[31]) {
    const int base = p * 61 * KPADW + f;
    if (!half) {
        #pragma unroll
        for (int s = 0; s < 31; ++s) K[s] = keyl[base + s * KPADW];
    } else {
        #pragma unroll
        for (int s = 0; s < 30; ++s) K[s] = keyl[base + (31 + s) * KPADW];
        K[30] = 0u;
    }
}

// ===== K_median: keys + iter-0 select + edge rule + table, ONE kernel ======
// Block = (b, 8-f chunk). Keys never leave LDS: kills the 78MB global
// round-trip + write-allocate RMW + 2 launch gaps that R16-R18 paid.
__global__ __launch_bounds__(256) void k_median(const float* __restrict__ x,
                                                float* __restrict__ wsTab) {
    __shared__ unsigned keyl[KLDS];           // [p][slot s][9-padded f]
    __shared__ unsigned short m0s[PERIOD * FCH];
    __shared__ float medBs[12 * FCH];

    const int d   = blockIdx.x;               // 1664 = 8*208, bijective swizzle
    const int blk = (d & 7) * 208 + (d >> 3);
    const int b   = blk & 63;
    const int ch  = blk >> 6;                 // 0..25
    const int f0  = ch * FCH;
    const int t   = threadIdx.x;

    // sentinel init: every (p, c=121) halfword must read 0xFFFF
    for (int i = t; i < KLDS; i += NT) keyl[i] = 0xFFFFFFFFu;
    __syncthreads();

    // ---- phase 1: rolling 13-window -> keys into LDS ----------------------
    {
        const int f   = t & 7;
        const int seg = t >> 3;               // 0..31, each 91 l-steps
        const int fe  = (f0 + f < NF) ? (f0 + f) : (NF - 1);
        const float* xb = x + (size_t)b * (LROW * NF) + fe;
        const int l0 = seg * 91;
        int c = l0 / PERIOD;
        int p = l0 - c * PERIOD;
        unsigned short* k16 = (unsigned short*)keyl;

        float r[13];
        float sum = 0.f;
        #pragma unroll
        for (int i = 0; i < 13; ++i) {
            int li = l0 - 7 + i; if (li < 0) li = 0;
            r[i] = xb[(size_t)li * NF];
            sum += r[i];
        }
        #pragma unroll 13
        for (int j = 0; j < 91; ++j) {
            const int l = l0 + j;
            int la = l + 6; if (la > LROW - 1) la = LROW - 1;
            float xn = xb[(size_t)la * NF];
            sum += xn - r[0];                  // sum = SA[l]
            unsigned k = quantk(r[7] - sum * R13);  // r[7] = x[l]
            if (l < LROW) {                    // guard: protects sentinel slots
                int idx = (p * 61 + (c >> 1)) * KPADW + f;
                k16[idx * 2 + (c & 1)] = (unsigned short)k;
            }
            #pragma unroll
            for (int i = 0; i < 12; ++i) r[i] = r[i + 1];
            r[12] = xn;
            ++p; if (p == PERIOD) { p = 0; ++c; }
        }
    }
    __syncthreads();

    // ---- phase A: iter-0 medians, split-K pairs (192 selects = 384 slots) -
    {   // sub-pass 0: slots t (p 0..15)
        const int sel = t >> 1, half = t & 1;
        const int f = sel & 7, p = sel >> 3;
        unsigned K[31]; loadK31(keyl, p, f, half, K);
        unsigned T = selN_split(K, 62);
        if (!half) m0s[p * FCH + f] = (unsigned short)T;
    }
    if (t < 128) {  // sub-pass 1: p 16..23 (waves 0-1; wave-uniform branch)
        const int sel = t >> 1, half = t & 1;
        const int f = sel & 7, p = 16 + (sel >> 3);
        unsigned K[31]; loadK31(keyl, p, f, half, K);
        unsigned T = selN_split(K, 62);
        if (!half) m0s[p * FCH + f] = (unsigned short)T;
    }
    __syncthreads();

    // ---- phase B: 12 edge phases via O(1) replacement rule ----------------
    if (t < 192) {
        const int sel = t >> 1, half = t & 1;
        const int f = sel & 7, e = sel >> 3;   // e 0..11
        const int p = (e < 6) ? e : e + 12;

        float m0[PERIOD];
        #pragma unroll
        for (int q = 0; q < PERIOD; ++q)
            m0[q] = dqmid(m0s[q * FCH + f]);

        float wph = 0.f, we = 0.f;             // static-index sums (rule #20)
        #pragma unroll
        for (int ee = 0; ee < 12; ++ee) if (ee == e) {
            const int pp = (ee < 6) ? ee : ee + 12;
            #pragma unroll
            for (int q = 0; q < 13; ++q) wph += m0[(pp + 18 + q) % 24];
            #pragma unroll
            for (int q = -6; q <= 6; ++q) {
                int aa = pp + q; if (aa < 0) aa = 0; if (aa > 23) aa = 23;
                we += m0[aa];
            }
        }

        unsigned K[31]; loadK31(keyl, p, f, half, K);
        unsigned m = (unsigned)m0s[p * FCH + f];
        // edge element: c=0 (p<6) or c=120 (p>=18) -> even c, low halfword
        unsigned xk = ((unsigned short*)keyl)
                      [((p * 61 + (p < 6 ? 0 : 60)) * KPADW + f) * 2];
        unsigned y = quantk(dqmid(xk) + (we - wph) * R13);

        int thr = (y > m) ? 61 : 63;           // v[61] or v[59] of OLD set
        unsigned v = selN_split(K, thr);
        bool up = (y > m) && (xk <= m);
        bool dn = (y < m) && (xk >= m);
        unsigned nm = up ? (y < v ? y : v) : (dn ? (y > v ? y : v) : m);
        if (!half) medBs[e * FCH + f] = dqmid(nm) + wph * R13;
    }
    __syncthreads();

    // ---- final: lm[24] + wt[24] per f -> wsTab[b][48][NF] -----------------
    if (t < FCH && f0 + t < NF) {
        const int f = t;
        float m0[PERIOD];
        #pragma unroll
        for (int q = 0; q < PERIOD; ++q)
            m0[q] = dqmid(m0s[q * FCH + f]);
        float W0[PERIOD];
        {
            float s = 0.f;
            #pragma unroll
            for (int q = 0; q < 13; ++q) s += m0[q];
            W0[0] = s;
            #pragma unroll
            for (int q = 1; q < PERIOD; ++q)
                W0[q] = W0[q - 1] + m0[(q + 12) % 24] - m0[q - 1];
        }
        float lm[PERIOD];
        #pragma unroll
        for (int e = 0; e < 12; ++e) {
            int p = (e < 6) ? e : e + 12;
            lm[p] = medBs[e * FCH + f];
        }
        #pragma unroll
        for (int p = 6; p < 18; ++p) lm[p] = m0[p] + W0[p - 6] * R13;
        float wt[PERIOD];
        {
            float s = 0.f;
            #pragma unroll
            for (int q = 0; q < 13; ++q) s += lm[q];
            wt[0] = s;
            #pragma unroll
            for (int q = 1; q < PERIOD; ++q)
                wt[q] = wt[q - 1] + lm[(q + 12) % 24] - lm[q - 1];
        }
        float* wrow = wsTab + (size_t)b * 48 * NF + (f0 + f);
        #pragma unroll
        for (int i = 0; i < PERIOD; ++i) {
            wrow[(size_t)i * NF]        = lm[i];
            wrow[(size_t)(24 + i) * NF] = wt[i];
        }
    }
}

// ===== K_out: coalesced outputs from ws table (R7-proven + NT stores) ======
__global__ __launch_bounds__(NT, 5) void stl_outputs(const float* __restrict__ x,
                                                     const float* __restrict__ ws,
                                                     float* __restrict__ out) {
    __shared__ float T[(LTILE + 12) * NF];

    const int d   = blockIdx.x;
    const int blk = (d & 7) * K2CHUNK + (d >> 3);
    const int b  = blk / NLT;
    const int kk = blk - b * NLT;
    const int l0 = kk * LTILE;
    const int t  = threadIdx.x;
    const float* xb = x + (size_t)b * (LROW * NF);

    if (kk != 0 && kk != NLT - 1) {
        const float2* s2 = (const float2*)(xb + (size_t)(l0 - 6) * NF);
        float2* t2 = (float2*)T;
        for (int i = t; i < (LTILE + 12) * NF / 2; i += NT) t2[i] = s2[i];
    } else {
        for (int i = t; i < (LTILE + 12) * NF; i += NT) {
            int lr = i / NF;
            int ff = i - lr * NF;
            T[i] = xb[(size_t)clampi(l0 - 6 + lr) * NF + ff];
        }
    }
    __syncthreads();

    if (t < NF) {
        float lm[PERIOD], wt[PERIOD];
        const float* wrow = ws + (size_t)b * 48 * NF + t;
        #pragma unroll
        for (int i = 0; i < PERIOD; ++i) lm[i] = wrow[(size_t)i * NF];
        #pragma unroll
        for (int i = 0; i < PERIOD; ++i) wt[i] = wrow[(size_t)(PERIOD + i) * NF];

        float s13 = 0.f;
        #pragma unroll
        for (int r = 0; r < 13; ++r) s13 += T[r * NF + t];

        const bool edgeLo = (kk == 0), edgeHi = (kk == NLT - 1);
        const size_t S = (size_t)NROWS * LROW;
        const size_t obase = (size_t)b * (LROW * NF) + (size_t)l0 * NF + (size_t)t;

        #pragma unroll
        for (int j = 0; j < LTILE; ++j) {
            float W = wt[(j + 18) % 24];
            if (edgeLo && j < 6) {
                float w = 0.f;
                #pragma unroll
                for (int jj = -6; jj <= 6; ++jj) { int m = j + jj; if (m < 0) m = 0; w += lm[m]; }
                W = w;
            }
            if (edgeHi && j >= 18) {
                float w = 0.f;
                #pragma unroll
                for (int jj = -6; jj <= 6; ++jj) { int m = j + jj; if (m > 23) m = 23; w += lm[m]; }
                W = w;
            }
            float tr = (s13 - W) * R13;
            float se = lm[j];
            float re = T[(j + 6) * NF + t] - tr - se;
            size_t o = obase + (size_t)(j * NF);
            __builtin_nontemporal_store(tr, &out[o]);
            __builtin_nontemporal_store(se, &out[S + o]);
            __builtin_nontemporal_store(re, &out[2 * S + o]);
            if (j < LTILE - 1)
                s13 += T[(j + 13) * NF + t] - T[j * NF + t];
        }
    }
}

extern "C" void kernel_launch(void* const* d_in, const int* in_sizes, int n_in,
                              void* d_out, int out_size, void* d_ws, size_t ws_size,
                              hipStream_t stream) {
    const float* x = (const float*)d_in[0];
    float* out = (float*)d_out;
    float* wsTab = (float*)d_ws;               // 64*48*207*4 = 2.54 MB
    (void)in_sizes; (void)n_in; (void)out_size; (void)ws_size;

    hipLaunchKernelGGL(k_median, dim3(NB * NCH), dim3(NT), 0, stream, x, wsTab);
    hipLaunchKernelGGL(stl_outputs, dim3(K2GRID), dim3(NT), 0, stream,
                       x, wsTab, out);
}